// Round 2
// 209.261 us; speedup vs baseline: 1.0223x; 1.0223x over previous
//
#include <hip/hip_runtime.h>

#define N_NODES 50000
#define N_EDGES 800000
#define CH 128
#define WT_PAD 136      // LDS row stride in shorts (272 B: 16B-aligned, 2-way-free banks)
#define DUMMY N_NODES   // g row 50000 is zeroed; CSR padding points here
#define SLOT_LOG 6      // 64 slots per node (max degree ~45 for Poisson(16))
#define AGG_HALF_BLKS 1563  // ceil(50000/32) blocks per channel-half
#define PREP_THREADS (128 * 256)

typedef __attribute__((ext_vector_type(8))) short short8;   // 8 bf16 = one MFMA A/B frag
typedef __attribute__((ext_vector_type(4))) float floatx4;  // MFMA C/D frag / NT stores

__device__ __forceinline__ short f2bf(float f) {  // RNE float->bf16
    union { float f; unsigned u; } v; v.f = f;
    unsigned r = v.u + 0x7fff + ((v.u >> 16) & 1);
    return (short)(r >> 16);
}
__device__ __forceinline__ float bflo(unsigned u) {
    union { unsigned u; float f; } v; v.u = u << 16; return v.f;
}
__device__ __forceinline__ float bfhi(unsigned u) {
    union { unsigned u; float f; } v; v.u = u & 0xffff0000u; return v.f;
}

// ---------------- prep: weights transpose/fuse + zero counts + DUMMY prefill ----------
// sorted_src is fully pre-filled with DUMMY so no per-node tail padding is needed later.

__global__ __launch_bounds__(256) void prep_kernel(const float* __restrict__ W1,
                                                   const float* __restrict__ W2,
                                                   const float* __restrict__ W3,
                                                   const float* __restrict__ b2,
                                                   const float* __restrict__ b3,
                                                   unsigned short* __restrict__ Wt1,
                                                   unsigned short* __restrict__ Wt23,
                                                   float* __restrict__ b23,
                                                   int* __restrict__ counts,
                                                   unsigned short* __restrict__ sorted_src,
                                                   unsigned int* __restrict__ gdummy) {
    int i = blockIdx.x * blockDim.x + threadIdx.x;   // 128*256 = 32768 threads
    if (i < 128 * 128) {
        int n = i >> 7, k = i & 127;
        Wt1[i] = (unsigned short)f2bf(W1[k * 128 + n]);
        float w = (n < 64) ? W2[k * 64 + n] : W3[k * 64 + (n - 64)];
        Wt23[i] = (unsigned short)f2bf(w);
    } else if (i < 128 * 128 + 128) {
        int k2 = i - 128 * 128;
        b23[k2] = (k2 < 64) ? b2[k2] : b3[k2 - 64];
    } else if (i < 128 * 128 + 192) {
        gdummy[i - (128 * 128 + 128)] = 0;           // 64 uints = 128 bf16 zeros
    }
    for (int j = i; j < N_NODES; j += PREP_THREADS) counts[j] = 0;
    // prefill all 64 slots/node with DUMMY (6.4 MB): replaces per-node tail padding
    const unsigned dpat = ((unsigned)DUMMY) | (((unsigned)DUMMY) << 16);
    uint4 dfill = make_uint4(dpat, dpat, dpat, dpat);
    uint4* sp = (uint4*)sorted_src;
    for (int j = i; j < (N_NODES << SLOT_LOG) / 8; j += PREP_THREADS) sp[j] = dfill;
}

// ---------------- CSR build: fused rank+scatter (one pass over edges) ------------------
// atomicAdd's return IS the slot index; fixed 64-slot rows need no prefix scan.

__global__ void rank_scatter(const int* __restrict__ ei, int* __restrict__ counts,
                             unsigned short* __restrict__ sorted_src) {
    int e = blockIdx.x * blockDim.x + threadIdx.x;
    if (e < N_EDGES) {
        int src = __builtin_nontemporal_load(ei + e);
        int dst = __builtin_nontemporal_load(ei + N_EDGES + e);
        int r = atomicAdd(&counts[dst], 1);
        if (r < 64) sorted_src[(dst << SLOT_LOG) + r] = (unsigned short)src;  // guard rows
    }
}

// ---------------- MFMA GEMM: g[n][ch] = bf16( dinv[n] * sum_c A[n][c]*W[c][ch] ) -------
// dinv is computed on the fly as rsqrt(deg+1); deg-0 nodes get rsqrt(1)=1 automatically.

template <bool A_BF16>
__global__ __launch_bounds__(256) void gemm_mfma(const void* __restrict__ Ain,
                                                 const unsigned short* __restrict__ Wt,
                                                 const int* __restrict__ degs,
                                                 unsigned short* __restrict__ g) {
    __shared__ unsigned short lds[128 * WT_PAD];  // 34816 B; reused by epilogue
    int tid = threadIdx.x;
    int wave = tid >> 6, lane = tid & 63;
    int quad = lane >> 4, ln = lane & 15;

    {   // stage Wt (16384 shorts)
        int r = tid >> 1, h = tid & 1;
        const int4* src = (const int4*)(Wt + r * 128 + h * 64);
#pragma unroll
        for (int i = 0; i < 8; ++i)
            *(int4*)&lds[r * WT_PAD + h * 64 + i * 8] = src[i];
    }

    int row_base = blockIdx.x * 64 + wave * 16;
    int arow = row_base + ln;
    bool ok = arow < N_NODES;
    short8 afrag[4];
    if (A_BF16) {
        const unsigned short* A = (const unsigned short*)Ain;
#pragma unroll
        for (int kk = 0; kk < 4; ++kk) {
            short8 v = {};
            if (ok) v = *(const short8*)(A + arow * 128 + kk * 32 + quad * 8);
            afrag[kk] = v;
        }
    } else {
        const float* A = (const float*)Ain;
#pragma unroll
        for (int kk = 0; kk < 4; ++kk) {
            short8 v = {};
            if (ok) {
                const floatx4* p = (const floatx4*)(A + arow * 128 + kk * 32 + quad * 8);
                floatx4 fa = p[0], fb = p[1];
                v[0] = f2bf(fa.x); v[1] = f2bf(fa.y); v[2] = f2bf(fa.z); v[3] = f2bf(fa.w);
                v[4] = f2bf(fb.x); v[5] = f2bf(fb.y); v[6] = f2bf(fb.z); v[7] = f2bf(fb.w);
            }
            afrag[kk] = v;
        }
    }
    __syncthreads();

    floatx4 acc[8] = {};
#pragma unroll
    for (int n0 = 0; n0 < 8; ++n0) {
#pragma unroll
        for (int kk = 0; kk < 4; ++kk) {
            short8 b = *(const short8*)&lds[(n0 * 16 + ln) * WT_PAD + kk * 32 + quad * 8];
            acc[n0] = __builtin_amdgcn_mfma_f32_16x16x32_bf16(afrag[kk], b, acc[n0], 0, 0, 0);
        }
    }

    __syncthreads();  // done with Wt; reuse LDS for epilogue transpose
    unsigned short* st = &lds[wave * 16 * WT_PAD];
    float dv[4];
#pragma unroll
    for (int r = 0; r < 4; ++r) {
        int node = row_base + quad * 4 + r;
        dv[r] = (node < N_NODES) ? rsqrtf((float)(degs[node] + 1)) : 0.f;
    }
#pragma unroll
    for (int n0 = 0; n0 < 8; ++n0)
#pragma unroll
        for (int r = 0; r < 4; ++r)
            st[(quad * 4 + r) * WT_PAD + n0 * 16 + ln] =
                (unsigned short)f2bf(acc[n0][r] * dv[r]);
    __syncthreads();

#pragma unroll
    for (int i = 0; i < 4; ++i) {
        int row = i * 4 + quad;
        int node = row_base + row;
        short8 v = *(const short8*)&st[row * WT_PAD + ln * 8];
        if (node < N_NODES) *(short8*)(g + node * 128 + ln * 8) = v;
    }
}

// ---------------- aggregation (bf16 gather, channel-split phases; LDS-free) ------------

template <int MODE>  // 0: bf16 out [N][128]; 1: fp32 split out (x1 | x2 by half)
__global__ __launch_bounds__(256) void aggregate_bf16(const unsigned short* __restrict__ g,
                                                      const int* __restrict__ degs,
                                                      const unsigned short* __restrict__ srcs,
                                                      const float* __restrict__ bias,
                                                      void* __restrict__ outp) {
    int h = 0, nb = blockIdx.x;
    if (nb >= AGG_HALF_BLKS) { h = 1; nb -= AGG_HALF_BLKS; }
    int n = nb * 32 + (threadIdx.x >> 3);
    if (n >= N_NODES) return;
    int c4 = threadIdx.x & 7;                   // uint4 index within the half-row
    int hoff = h * 8;
    const uint4* grow = (const uint4*)g;        // 16 uint4 per full row
    uint4 u = grow[n * 16 + hoff + c4];         // self-loop term
    float a0 = bflo(u.x), a1 = bfhi(u.x), a2 = bflo(u.y), a3 = bfhi(u.y);
    float a4 = bflo(u.z), a5 = bfhi(u.z), a6 = bflo(u.w), a7 = bfhi(u.w);
    float c0 = 0.f, c1 = 0.f, c2 = 0.f, c3 = 0.f, c5 = 0.f, c6 = 0.f, c7 = 0.f, c8 = 0.f;
    int deg = degs[n];
    int beg = n << SLOT_LOG;
    int pend = beg + ((deg + 3) & ~3);          // pad slots hold DUMMY (zero row)
    int e = beg;
    for (; e + 8 <= pend; e += 8) {
        ushort4 sa = *(const ushort4*)&srcs[e];
        ushort4 sb = *(const ushort4*)&srcs[e + 4];
        uint4 v0 = grow[sa.x * 16 + hoff + c4];
        uint4 v1 = grow[sa.y * 16 + hoff + c4];
        uint4 v2 = grow[sa.z * 16 + hoff + c4];
        uint4 v3 = grow[sa.w * 16 + hoff + c4];
        uint4 v4 = grow[sb.x * 16 + hoff + c4];
        uint4 v5 = grow[sb.y * 16 + hoff + c4];
        uint4 v6 = grow[sb.z * 16 + hoff + c4];
        uint4 v7 = grow[sb.w * 16 + hoff + c4];
        a0 += bflo(v0.x); a1 += bfhi(v0.x); a2 += bflo(v0.y); a3 += bfhi(v0.y);
        a4 += bflo(v0.z); a5 += bfhi(v0.z); a6 += bflo(v0.w); a7 += bfhi(v0.w);
        c0 += bflo(v1.x); c1 += bfhi(v1.x); c2 += bflo(v1.y); c3 += bfhi(v1.y);
        c5 += bflo(v1.z); c6 += bfhi(v1.z); c7 += bflo(v1.w); c8 += bfhi(v1.w);
        a0 += bflo(v2.x); a1 += bfhi(v2.x); a2 += bflo(v2.y); a3 += bfhi(v2.y);
        a4 += bflo(v2.z); a5 += bfhi(v2.z); a6 += bflo(v2.w); a7 += bfhi(v2.w);
        c0 += bflo(v3.x); c1 += bfhi(v3.x); c2 += bflo(v3.y); c3 += bfhi(v3.y);
        c5 += bflo(v3.z); c6 += bfhi(v3.z); c7 += bflo(v3.w); c8 += bfhi(v3.w);
        a0 += bflo(v4.x); a1 += bfhi(v4.x); a2 += bflo(v4.y); a3 += bfhi(v4.y);
        a4 += bflo(v4.z); a5 += bfhi(v4.z); a6 += bflo(v4.w); a7 += bfhi(v4.w);
        c0 += bflo(v5.x); c1 += bfhi(v5.x); c2 += bflo(v5.y); c3 += bfhi(v5.y);
        c5 += bflo(v5.z); c6 += bfhi(v5.z); c7 += bflo(v5.w); c8 += bfhi(v5.w);
        a0 += bflo(v6.x); a1 += bfhi(v6.x); a2 += bflo(v6.y); a3 += bfhi(v6.y);
        a4 += bflo(v6.z); a5 += bfhi(v6.z); a6 += bflo(v6.w); a7 += bfhi(v6.w);
        c0 += bflo(v7.x); c1 += bfhi(v7.x); c2 += bflo(v7.y); c3 += bfhi(v7.y);
        c5 += bflo(v7.z); c6 += bfhi(v7.z); c7 += bflo(v7.w); c8 += bfhi(v7.w);
    }
    if (e < pend) {  // exactly one 4-wide chunk (pend-beg is a multiple of 4)
        ushort4 sa = *(const ushort4*)&srcs[e];
        uint4 v0 = grow[sa.x * 16 + hoff + c4];
        uint4 v1 = grow[sa.y * 16 + hoff + c4];
        uint4 v2 = grow[sa.z * 16 + hoff + c4];
        uint4 v3 = grow[sa.w * 16 + hoff + c4];
        a0 += bflo(v0.x); a1 += bfhi(v0.x); a2 += bflo(v0.y); a3 += bfhi(v0.y);
        a4 += bflo(v0.z); a5 += bfhi(v0.z); a6 += bflo(v0.w); a7 += bfhi(v0.w);
        c0 += bflo(v1.x); c1 += bfhi(v1.x); c2 += bflo(v1.y); c3 += bfhi(v1.y);
        c5 += bflo(v1.z); c6 += bfhi(v1.z); c7 += bflo(v1.w); c8 += bfhi(v1.w);
        a0 += bflo(v2.x); a1 += bfhi(v2.x); a2 += bflo(v2.y); a3 += bfhi(v2.y);
        a4 += bflo(v2.z); a5 += bfhi(v2.z); a6 += bflo(v2.w); a7 += bfhi(v2.w);
        c0 += bflo(v3.x); c1 += bfhi(v3.x); c2 += bflo(v3.y); c3 += bfhi(v3.y);
        c5 += bflo(v3.z); c6 += bfhi(v3.z); c7 += bflo(v3.w); c8 += bfhi(v3.w);
    }
    a0 += c0; a1 += c1; a2 += c2; a3 += c3; a4 += c5; a5 += c6; a6 += c7; a7 += c8;
    float d = rsqrtf((float)(deg + 1));
    float4 bv0 = ((const float4*)bias)[h * 16 + c4 * 2];
    float4 bv1 = ((const float4*)bias)[h * 16 + c4 * 2 + 1];
    float o0 = fmaxf(d * a0 + bv0.x, 0.f);
    float o1 = fmaxf(d * a1 + bv0.y, 0.f);
    float o2 = fmaxf(d * a2 + bv0.z, 0.f);
    float o3 = fmaxf(d * a3 + bv0.w, 0.f);
    float o4 = fmaxf(d * a4 + bv1.x, 0.f);
    float o5 = fmaxf(d * a5 + bv1.y, 0.f);
    float o6 = fmaxf(d * a6 + bv1.z, 0.f);
    float o7 = fmaxf(d * a7 + bv1.w, 0.f);
    if (MODE == 0) {
        uint4 w;
        w.x = ((unsigned)(unsigned short)f2bf(o0)) | (((unsigned)(unsigned short)f2bf(o1)) << 16);
        w.y = ((unsigned)(unsigned short)f2bf(o2)) | (((unsigned)(unsigned short)f2bf(o3)) << 16);
        w.z = ((unsigned)(unsigned short)f2bf(o4)) | (((unsigned)(unsigned short)f2bf(o5)) << 16);
        w.w = ((unsigned)(unsigned short)f2bf(o6)) | (((unsigned)(unsigned short)f2bf(o7)) << 16);
        ((uint4*)outp)[n * 16 + hoff + c4] = w;   // hidden is reused by gemm2: keep cached
    } else {
        // half 0 == x1 exactly; half 1 == x2 exactly (64 ch each, fp32)
        // nontemporal: final output stream must not evict the 12.8 MB gather working set
        float* out = (float*)outp + (size_t)h * N_NODES * 64;
        floatx4* o = (floatx4*)out + n * 16 + c4 * 2;
        floatx4 w0; w0.x = o0; w0.y = o1; w0.z = o2; w0.w = o3;
        floatx4 w1; w1.x = o4; w1.y = o5; w1.z = o6; w1.w = o7;
        __builtin_nontemporal_store(w0, o);
        __builtin_nontemporal_store(w1, o + 1);
    }
}

// ---------------- launch ----------------

extern "C" void kernel_launch(void* const* d_in, const int* in_sizes, int n_in,
                              void* d_out, int out_size, void* d_ws, size_t ws_size,
                              hipStream_t stream) {
    const float* x  = (const float*)d_in[0];
    const int*   ei = (const int*)d_in[1];   // [2, E] int32
    const float* W1 = (const float*)d_in[2];
    const float* b1 = (const float*)d_in[3];
    const float* W2 = (const float*)d_in[4];
    const float* b2 = (const float*)d_in[5];
    const float* W3 = (const float*)d_in[6];
    const float* b3 = (const float*)d_in[7];
    float* out = (float*)d_out;

    // Workspace layout (non-overlapping; g1 ends 25,383,168 < hidden 25,690,112)
    char* w = (char*)d_ws;
    int*            counts     = (int*)(w + 0);                    // 200000 B (ends as degree)
    unsigned short* sorted_src = (unsigned short*)(w + 3686400);   // 6.4 MB (64 slots/node)
    unsigned short* Wt1        = (unsigned short*)(w + 10485760);  // 32768 B
    unsigned short* Wt23       = (unsigned short*)(w + 10518528);  // 32768 B
    float*          b23        = (float*)(w + 10551296);           // 512 B
    unsigned short* g1         = (unsigned short*)(w + 12582912);  // 12,800,256 B (+dummy row)
    unsigned short* hidden     = (unsigned short*)(w + 25690112);  // 12,800,000 B

    // prep (weights + zero counts + DUMMY prefill + zero dummy g row), then fused CSR build
    prep_kernel<<<128, 256, 0, stream>>>(W1, W2, W3, b2, b3, Wt1, Wt23, b23, counts,
                                         sorted_src, (unsigned int*)(g1 + N_NODES * 128));
    rank_scatter<<<(N_EDGES + 255) / 256, 256, 0, stream>>>(ei, counts, sorted_src);

    const int gemm_blocks = (N_NODES + 63) / 64;  // 782
    const int agg_blocks = 2 * AGG_HALF_BLKS;     // 3126 (two channel-half phases)

    // layer 1: g1 = bf16(dinv * (x @ W1)); hidden = bf16(relu(dinv*(self+sum)+b1))
    gemm_mfma<false><<<gemm_blocks, 256, 0, stream>>>(x, Wt1, counts, g1);
    aggregate_bf16<0><<<agg_blocks, 256, 0, stream>>>(g1, counts, sorted_src, b1, hidden);

    // layers 2+3 fused: g1 = bf16(dinv * (hidden @ [W2|W3])); out = relu split
    gemm_mfma<true><<<gemm_blocks, 256, 0, stream>>>(hidden, Wt23, counts, g1);
    aggregate_bf16<1><<<agg_blocks, 256, 0, stream>>>(g1, counts, sorted_src, b23, out);
}

// Round 3
// 190.874 us; speedup vs baseline: 1.1208x; 1.0963x over previous
//
#include <hip/hip_runtime.h>

#define N_NODES 50000
#define N_EDGES 800000
#define CH 128
#define WT_PAD 136      // LDS row stride in shorts (272 B: 16B-aligned, 2-way-free banks)
#define DUMMY N_NODES   // g row 50000 is zeroed; CSR padding points here
#define SLOT_LOG 6      // 64 slots per node (max degree ~45 for Poisson(16))
#define AGG_HALF_BLKS 1563  // ceil(50000/32) blocks per channel-half

#define NBUCK 391       // ceil(50000/128) buckets of 128 nodes
#define BUCK_CAP 3072   // mean 2046, sigma ~45 -> +22 sigma headroom
#define EPB 4096        // edges per partition block
#define PART_BLOCKS 196 // ceil(800000/4096)

typedef __attribute__((ext_vector_type(8))) short short8;   // 8 bf16 = one MFMA A/B frag
typedef __attribute__((ext_vector_type(4))) float floatx4;  // MFMA C/D frag / NT stores

__device__ __forceinline__ short f2bf(float f) {  // RNE float->bf16
    union { float f; unsigned u; } v; v.f = f;
    unsigned r = v.u + 0x7fff + ((v.u >> 16) & 1);
    return (short)(r >> 16);
}
__device__ __forceinline__ float bflo(unsigned u) {
    union { unsigned u; float f; } v; v.u = u << 16; return v.f;
}
__device__ __forceinline__ float bfhi(unsigned u) {
    union { unsigned u; float f; } v; v.u = u & 0xffff0000u; return v.f;
}

// ---------------- prep: weights transpose/fuse + zero bucket counters -----------------
// (counts and sorted_src no longer need prefill: csr_build writes every byte of both)

__global__ __launch_bounds__(256) void prep_kernel(const float* __restrict__ W1,
                                                   const float* __restrict__ W2,
                                                   const float* __restrict__ W3,
                                                   const float* __restrict__ b2,
                                                   const float* __restrict__ b3,
                                                   unsigned short* __restrict__ Wt1,
                                                   unsigned short* __restrict__ Wt23,
                                                   float* __restrict__ b23,
                                                   int* __restrict__ bucket_cnt,
                                                   unsigned int* __restrict__ gdummy) {
    int i = blockIdx.x * blockDim.x + threadIdx.x;   // 66*256 = 16896 threads
    if (i < 128 * 128) {
        int n = i >> 7, k = i & 127;
        Wt1[i] = (unsigned short)f2bf(W1[k * 128 + n]);
        float w = (n < 64) ? W2[k * 64 + n] : W3[k * 64 + (n - 64)];
        Wt23[i] = (unsigned short)f2bf(w);
    } else if (i < 128 * 128 + 128) {
        int k2 = i - 128 * 128;
        b23[k2] = (k2 < 64) ? b2[k2] : b3[k2 - 64];
    } else if (i < 128 * 128 + 192) {
        gdummy[i - (128 * 128 + 128)] = 0;           // 64 uints = 128 bf16 zeros
    }
    if (i < NBUCK) bucket_cnt[i] = 0;
}

// ---------------- Phase A: radix-partition edges into 391 dst-buckets -----------------
// Per block: LDS histogram -> LDS scan -> one global atomic per (block,bucket) ->
// bucket-sorted LDS staging -> coalesced u32 flush. ~77k global atomics total (was 800k),
// all global writes full-line.

__global__ __launch_bounds__(256) void partition(const int* __restrict__ ei,
                                                 int* __restrict__ bucket_cnt,
                                                 unsigned* __restrict__ bucket_data) {
    __shared__ int hcnt[512], hscan[512], htmp[512];   // hist + inclusive scan (ping-pong)
    __shared__ int s_shift[512];                        // base_g - base_l per bucket
    __shared__ unsigned stg[EPB];                       // bucket-sorted packed edges
    __shared__ int dsti[EPB];                           // global index per staged edge
    int tid = threadIdx.x;
    int e0 = blockIdx.x * EPB;

    for (int i = tid; i < 512; i += 256) hcnt[i] = 0;
    __syncthreads();
    for (int j = tid; j < EPB; j += 256) {
        int e = e0 + j;
        if (e < N_EDGES) atomicAdd(&hcnt[ei[N_EDGES + e] >> 7], 1);
    }
    __syncthreads();
    for (int i = tid; i < 512; i += 256) hscan[i] = hcnt[i];
    __syncthreads();
    for (int off = 1; off < 512; off <<= 1) {           // Hillis-Steele inclusive scan
        for (int i = tid; i < 512; i += 256) htmp[i] = hscan[i] + (i >= off ? hscan[i - off] : 0);
        __syncthreads();
        for (int i = tid; i < 512; i += 256) hscan[i] = htmp[i];
        __syncthreads();
    }
    // exclusive base_l = hscan - hcnt; allocate global space; cursor starts at base_l
    for (int b = tid; b < NBUCK; b += 256) {
        int c = hcnt[b];
        int excl = hscan[b] - c;
        int g = (c > 0) ? atomicAdd(&bucket_cnt[b], c) : 0;
        s_shift[b] = g - excl;
        htmp[b] = excl;                                 // htmp reused as cursor
    }
    __syncthreads();
    for (int j = tid; j < EPB; j += 256) {              // stage bucket-sorted
        int e = e0 + j;
        if (e < N_EDGES) {
            int src = ei[e];
            int d = ei[N_EDGES + e];
            int b = d >> 7;
            int pos = atomicAdd(&htmp[b], 1);           // LDS cursor
            stg[pos] = ((unsigned)(d & 127) << 16) | (unsigned)src;
            int gidx = s_shift[b] + pos;                // index within bucket region
            dsti[pos] = (gidx < BUCK_CAP) ? (b * BUCK_CAP + gidx) : -1;
        }
    }
    __syncthreads();
    int tot = N_EDGES - e0; if (tot > EPB) tot = EPB;
    for (int j = tid; j < tot; j += 256) {              // coalesced runs per bucket
        int di = dsti[j];
        if (di >= 0) bucket_data[di] = stg[j];
    }
}

// ---------------- Phase B: per-bucket CSR rows built entirely in LDS ------------------
// LDS atomics for ranks (no fabric), DUMMY pad in LDS, fully coalesced flush of
// counts + slot rows. One block per bucket (128 nodes x 64 slots = 16 KB).

__global__ __launch_bounds__(256) void csr_build(const unsigned* __restrict__ bucket_data,
                                                 const int* __restrict__ bucket_cnt,
                                                 int* __restrict__ counts,
                                                 unsigned short* __restrict__ sorted_src) {
    __shared__ uint4 slots4[1024];                      // 128 rows x 64 shorts = 16 KB
    __shared__ int ctr[128];
    unsigned short* slots = (unsigned short*)slots4;
    int tid = threadIdx.x, b = blockIdx.x;

    for (int i = tid; i < 128; i += 256) ctr[i] = 0;
    const unsigned dpat = ((unsigned)DUMMY) | (((unsigned)DUMMY) << 16);
    for (int i = tid; i < 1024; i += 256) slots4[i] = make_uint4(dpat, dpat, dpat, dpat);
    __syncthreads();

    int cnt = bucket_cnt[b]; if (cnt > BUCK_CAP) cnt = BUCK_CAP;
    const unsigned* bd = bucket_data + b * BUCK_CAP;
    for (int j = tid; j < cnt; j += 256) {
        unsigned w = bd[j];
        int dl = (int)(w >> 16);
        int r = atomicAdd(&ctr[dl], 1);                 // LDS atomic: fast
        if (r < 64) slots[(dl << 6) + r] = (unsigned short)(w & 0xffffu);
    }
    __syncthreads();

    int node0 = b << 7;
    for (int i = tid; i < 128; i += 256)
        if (node0 + i < N_NODES) counts[node0 + i] = ctr[i];
    uint4* gs = (uint4*)(sorted_src + ((size_t)node0 << SLOT_LOG));
    for (int k = tid; k < 1024; k += 256) {             // 8 uint4 per row, coalesced
        int row = k >> 3;
        if (node0 + row < N_NODES) gs[k] = slots4[k];
    }
}

// ---------------- MFMA GEMM: g[n][ch] = bf16( dinv[n] * sum_c A[n][c]*W[c][ch] ) -------
// dinv is computed on the fly as rsqrt(deg+1); deg-0 nodes get rsqrt(1)=1 automatically.

template <bool A_BF16>
__global__ __launch_bounds__(256) void gemm_mfma(const void* __restrict__ Ain,
                                                 const unsigned short* __restrict__ Wt,
                                                 const int* __restrict__ degs,
                                                 unsigned short* __restrict__ g) {
    __shared__ unsigned short lds[128 * WT_PAD];  // 34816 B; reused by epilogue
    int tid = threadIdx.x;
    int wave = tid >> 6, lane = tid & 63;
    int quad = lane >> 4, ln = lane & 15;

    {   // stage Wt (16384 shorts)
        int r = tid >> 1, h = tid & 1;
        const int4* src = (const int4*)(Wt + r * 128 + h * 64);
#pragma unroll
        for (int i = 0; i < 8; ++i)
            *(int4*)&lds[r * WT_PAD + h * 64 + i * 8] = src[i];
    }

    int row_base = blockIdx.x * 64 + wave * 16;
    int arow = row_base + ln;
    bool ok = arow < N_NODES;
    short8 afrag[4];
    if (A_BF16) {
        const unsigned short* A = (const unsigned short*)Ain;
#pragma unroll
        for (int kk = 0; kk < 4; ++kk) {
            short8 v = {};
            if (ok) v = *(const short8*)(A + arow * 128 + kk * 32 + quad * 8);
            afrag[kk] = v;
        }
    } else {
        const float* A = (const float*)Ain;
#pragma unroll
        for (int kk = 0; kk < 4; ++kk) {
            short8 v = {};
            if (ok) {
                const floatx4* p = (const floatx4*)(A + arow * 128 + kk * 32 + quad * 8);
                floatx4 fa = p[0], fb = p[1];
                v[0] = f2bf(fa.x); v[1] = f2bf(fa.y); v[2] = f2bf(fa.z); v[3] = f2bf(fa.w);
                v[4] = f2bf(fb.x); v[5] = f2bf(fb.y); v[6] = f2bf(fb.z); v[7] = f2bf(fb.w);
            }
            afrag[kk] = v;
        }
    }
    __syncthreads();

    floatx4 acc[8] = {};
#pragma unroll
    for (int n0 = 0; n0 < 8; ++n0) {
#pragma unroll
        for (int kk = 0; kk < 4; ++kk) {
            short8 b = *(const short8*)&lds[(n0 * 16 + ln) * WT_PAD + kk * 32 + quad * 8];
            acc[n0] = __builtin_amdgcn_mfma_f32_16x16x32_bf16(afrag[kk], b, acc[n0], 0, 0, 0);
        }
    }

    __syncthreads();  // done with Wt; reuse LDS for epilogue transpose
    unsigned short* st = &lds[wave * 16 * WT_PAD];
    float dv[4];
#pragma unroll
    for (int r = 0; r < 4; ++r) {
        int node = row_base + quad * 4 + r;
        dv[r] = (node < N_NODES) ? rsqrtf((float)(degs[node] + 1)) : 0.f;
    }
#pragma unroll
    for (int n0 = 0; n0 < 8; ++n0)
#pragma unroll
        for (int r = 0; r < 4; ++r)
            st[(quad * 4 + r) * WT_PAD + n0 * 16 + ln] =
                (unsigned short)f2bf(acc[n0][r] * dv[r]);
    __syncthreads();

#pragma unroll
    for (int i = 0; i < 4; ++i) {
        int row = i * 4 + quad;
        int node = row_base + row;
        short8 v = *(const short8*)&st[row * WT_PAD + ln * 8];
        if (node < N_NODES) *(short8*)(g + node * 128 + ln * 8) = v;
    }
}

// ---------------- aggregation (bf16 gather, channel-split phases; LDS-free) ------------

template <int MODE>  // 0: bf16 out [N][128]; 1: fp32 split out (x1 | x2 by half)
__global__ __launch_bounds__(256) void aggregate_bf16(const unsigned short* __restrict__ g,
                                                      const int* __restrict__ degs,
                                                      const unsigned short* __restrict__ srcs,
                                                      const float* __restrict__ bias,
                                                      void* __restrict__ outp) {
    int h = 0, nb = blockIdx.x;
    if (nb >= AGG_HALF_BLKS) { h = 1; nb -= AGG_HALF_BLKS; }
    int n = nb * 32 + (threadIdx.x >> 3);
    if (n >= N_NODES) return;
    int c4 = threadIdx.x & 7;                   // uint4 index within the half-row
    int hoff = h * 8;
    const uint4* grow = (const uint4*)g;        // 16 uint4 per full row
    uint4 u = grow[n * 16 + hoff + c4];         // self-loop term
    float a0 = bflo(u.x), a1 = bfhi(u.x), a2 = bflo(u.y), a3 = bfhi(u.y);
    float a4 = bflo(u.z), a5 = bfhi(u.z), a6 = bflo(u.w), a7 = bfhi(u.w);
    float c0 = 0.f, c1 = 0.f, c2 = 0.f, c3 = 0.f, c5 = 0.f, c6 = 0.f, c7 = 0.f, c8 = 0.f;
    int deg = degs[n];
    int degc = deg > 64 ? 64 : deg;
    int beg = n << SLOT_LOG;
    int pend = beg + ((degc + 3) & ~3);         // pad slots hold DUMMY (zero row)
    int e = beg;
    for (; e + 8 <= pend; e += 8) {
        ushort4 sa = *(const ushort4*)&srcs[e];
        ushort4 sb = *(const ushort4*)&srcs[e + 4];
        uint4 v0 = grow[sa.x * 16 + hoff + c4];
        uint4 v1 = grow[sa.y * 16 + hoff + c4];
        uint4 v2 = grow[sa.z * 16 + hoff + c4];
        uint4 v3 = grow[sa.w * 16 + hoff + c4];
        uint4 v4 = grow[sb.x * 16 + hoff + c4];
        uint4 v5 = grow[sb.y * 16 + hoff + c4];
        uint4 v6 = grow[sb.z * 16 + hoff + c4];
        uint4 v7 = grow[sb.w * 16 + hoff + c4];
        a0 += bflo(v0.x); a1 += bfhi(v0.x); a2 += bflo(v0.y); a3 += bfhi(v0.y);
        a4 += bflo(v0.z); a5 += bfhi(v0.z); a6 += bflo(v0.w); a7 += bfhi(v0.w);
        c0 += bflo(v1.x); c1 += bfhi(v1.x); c2 += bflo(v1.y); c3 += bfhi(v1.y);
        c5 += bflo(v1.z); c6 += bfhi(v1.z); c7 += bflo(v1.w); c8 += bfhi(v1.w);
        a0 += bflo(v2.x); a1 += bfhi(v2.x); a2 += bflo(v2.y); a3 += bfhi(v2.y);
        a4 += bflo(v2.z); a5 += bfhi(v2.z); a6 += bflo(v2.w); a7 += bfhi(v2.w);
        c0 += bflo(v3.x); c1 += bfhi(v3.x); c2 += bflo(v3.y); c3 += bfhi(v3.y);
        c5 += bflo(v3.z); c6 += bfhi(v3.z); c7 += bflo(v3.w); c8 += bfhi(v3.w);
        a0 += bflo(v4.x); a1 += bfhi(v4.x); a2 += bflo(v4.y); a3 += bfhi(v4.y);
        a4 += bflo(v4.z); a5 += bfhi(v4.z); a6 += bflo(v4.w); a7 += bfhi(v4.w);
        c0 += bflo(v5.x); c1 += bfhi(v5.x); c2 += bflo(v5.y); c3 += bfhi(v5.y);
        c5 += bflo(v5.z); c6 += bfhi(v5.z); c7 += bflo(v5.w); c8 += bfhi(v5.w);
        a0 += bflo(v6.x); a1 += bfhi(v6.x); a2 += bflo(v6.y); a3 += bfhi(v6.y);
        a4 += bflo(v6.z); a5 += bfhi(v6.z); a6 += bflo(v6.w); a7 += bfhi(v6.w);
        c0 += bflo(v7.x); c1 += bfhi(v7.x); c2 += bflo(v7.y); c3 += bfhi(v7.y);
        c5 += bflo(v7.z); c6 += bfhi(v7.z); c7 += bflo(v7.w); c8 += bfhi(v7.w);
    }
    if (e < pend) {  // exactly one 4-wide chunk (pend-beg is a multiple of 4)
        ushort4 sa = *(const ushort4*)&srcs[e];
        uint4 v0 = grow[sa.x * 16 + hoff + c4];
        uint4 v1 = grow[sa.y * 16 + hoff + c4];
        uint4 v2 = grow[sa.z * 16 + hoff + c4];
        uint4 v3 = grow[sa.w * 16 + hoff + c4];
        a0 += bflo(v0.x); a1 += bfhi(v0.x); a2 += bflo(v0.y); a3 += bfhi(v0.y);
        a4 += bflo(v0.z); a5 += bfhi(v0.z); a6 += bflo(v0.w); a7 += bfhi(v0.w);
        c0 += bflo(v1.x); c1 += bfhi(v1.x); c2 += bflo(v1.y); c3 += bfhi(v1.y);
        c5 += bflo(v1.z); c6 += bfhi(v1.z); c7 += bflo(v1.w); c8 += bfhi(v1.w);
        a0 += bflo(v2.x); a1 += bfhi(v2.x); a2 += bflo(v2.y); a3 += bfhi(v2.y);
        a4 += bflo(v2.z); a5 += bfhi(v2.z); a6 += bflo(v2.w); a7 += bfhi(v2.w);
        c0 += bflo(v3.x); c1 += bfhi(v3.x); c2 += bflo(v3.y); c3 += bfhi(v3.y);
        c5 += bflo(v3.z); c6 += bfhi(v3.z); c7 += bflo(v3.w); c8 += bfhi(v3.w);
    }
    a0 += c0; a1 += c1; a2 += c2; a3 += c3; a4 += c5; a5 += c6; a6 += c7; a7 += c8;
    float d = rsqrtf((float)(deg + 1));
    float4 bv0 = ((const float4*)bias)[h * 16 + c4 * 2];
    float4 bv1 = ((const float4*)bias)[h * 16 + c4 * 2 + 1];
    float o0 = fmaxf(d * a0 + bv0.x, 0.f);
    float o1 = fmaxf(d * a1 + bv0.y, 0.f);
    float o2 = fmaxf(d * a2 + bv0.z, 0.f);
    float o3 = fmaxf(d * a3 + bv0.w, 0.f);
    float o4 = fmaxf(d * a4 + bv1.x, 0.f);
    float o5 = fmaxf(d * a5 + bv1.y, 0.f);
    float o6 = fmaxf(d * a6 + bv1.z, 0.f);
    float o7 = fmaxf(d * a7 + bv1.w, 0.f);
    if (MODE == 0) {
        uint4 w;
        w.x = ((unsigned)(unsigned short)f2bf(o0)) | (((unsigned)(unsigned short)f2bf(o1)) << 16);
        w.y = ((unsigned)(unsigned short)f2bf(o2)) | (((unsigned)(unsigned short)f2bf(o3)) << 16);
        w.z = ((unsigned)(unsigned short)f2bf(o4)) | (((unsigned)(unsigned short)f2bf(o5)) << 16);
        w.w = ((unsigned)(unsigned short)f2bf(o6)) | (((unsigned)(unsigned short)f2bf(o7)) << 16);
        ((uint4*)outp)[n * 16 + hoff + c4] = w;   // hidden is reused by gemm2: keep cached
    } else {
        // half 0 == x1 exactly; half 1 == x2 exactly (64 ch each, fp32)
        // nontemporal: final output stream must not evict the 12.8 MB gather working set
        float* out = (float*)outp + (size_t)h * N_NODES * 64;
        floatx4* o = (floatx4*)out + n * 16 + c4 * 2;
        floatx4 w0; w0.x = o0; w0.y = o1; w0.z = o2; w0.w = o3;
        floatx4 w1; w1.x = o4; w1.y = o5; w1.z = o6; w1.w = o7;
        __builtin_nontemporal_store(w0, o);
        __builtin_nontemporal_store(w1, o + 1);
    }
}

// ---------------- launch ----------------

extern "C" void kernel_launch(void* const* d_in, const int* in_sizes, int n_in,
                              void* d_out, int out_size, void* d_ws, size_t ws_size,
                              hipStream_t stream) {
    const float* x  = (const float*)d_in[0];
    const int*   ei = (const int*)d_in[1];   // [2, E] int32
    const float* W1 = (const float*)d_in[2];
    const float* b1 = (const float*)d_in[3];
    const float* W2 = (const float*)d_in[4];
    const float* b2 = (const float*)d_in[5];
    const float* W3 = (const float*)d_in[6];
    const float* b3 = (const float*)d_in[7];
    float* out = (float*)d_out;

    // Workspace layout (non-overlapping; total 37,083,392 B < previously-proven 38,490,112)
    char* w = (char*)d_ws;
    int*            counts      = (int*)(w + 0);                   // 200,000 B (true degree)
    int*            bucket_cnt  = (int*)(w + 200704);              // 1,564 B
    unsigned short* Wt1         = (unsigned short*)(w + 204800);   // 32,768 B
    unsigned short* Wt23        = (unsigned short*)(w + 237568);   // 32,768 B
    float*          b23         = (float*)(w + 270336);            // 512 B
    unsigned*       bucket_data = (unsigned*)(w + 278528);         // 4,804,608 B
    unsigned short* sorted_src  = (unsigned short*)(w + 5083136);  // 6,400,000 B
    unsigned short* g1          = (unsigned short*)(w + 11483136); // 12,800,256 B (+dummy row)
    unsigned short* hidden      = (unsigned short*)(w + 24283392); // 12,800,000 B

    // prep (weights + bucket_cnt zero + zero dummy g row), then 2-phase CSR build
    prep_kernel<<<66, 256, 0, stream>>>(W1, W2, W3, b2, b3, Wt1, Wt23, b23, bucket_cnt,
                                        (unsigned int*)(g1 + N_NODES * 128));
    partition<<<PART_BLOCKS, 256, 0, stream>>>(ei, bucket_cnt, bucket_data);
    csr_build<<<NBUCK, 256, 0, stream>>>(bucket_data, bucket_cnt, counts, sorted_src);

    const int gemm_blocks = (N_NODES + 63) / 64;  // 782
    const int agg_blocks = 2 * AGG_HALF_BLKS;     // 3126 (two channel-half phases)

    // layer 1: g1 = bf16(dinv * (x @ W1)); hidden = bf16(relu(dinv*(self+sum)+b1))
    gemm_mfma<false><<<gemm_blocks, 256, 0, stream>>>(x, Wt1, counts, g1);
    aggregate_bf16<0><<<agg_blocks, 256, 0, stream>>>(g1, counts, sorted_src, b1, hidden);

    // layers 2+3 fused: g1 = bf16(dinv * (hidden @ [W2|W3])); out = relu split
    gemm_mfma<true><<<gemm_blocks, 256, 0, stream>>>(hidden, Wt23, counts, g1);
    aggregate_bf16<1><<<agg_blocks, 256, 0, stream>>>(g1, counts, sorted_src, b23, out);
}